// Round 11
// baseline (266.901 us; speedup 1.0000x reference)
//
#include <hip/hip_runtime.h>
#include <math.h>

#define NN 4096
#define DD 256
#define HH 4
#define SPLIT 8
#define BKG 64

typedef short short8 __attribute__((ext_vector_type(8)));
typedef float float4v __attribute__((ext_vector_type(4)));

__device__ __forceinline__ unsigned short f2bf(float f) {
  unsigned u = __float_as_uint(f);
  u += 0x7FFF + ((u >> 16) & 1);   // RNE
  return (unsigned short)(u >> 16);
}
__device__ __forceinline__ unsigned f2bf_pk(float a, float b) {
  unsigned ua = __float_as_uint(a); ua += 0x7FFF + ((ua >> 16) & 1);
  unsigned ub = __float_as_uint(b); ub += 0x7FFF + ((ub >> 16) & 1);
  return __builtin_amdgcn_perm(ub, ua, 0x07060302);
}
__device__ __forceinline__ void gld16(void* lds, const void* gp) {
  __builtin_amdgcn_global_load_lds(
      (const __attribute__((address_space(1))) unsigned int*)gp,
      (__attribute__((address_space(3))) unsigned int*)lds, 16, 0, 0);
}

// ---------------- zero hp (atomic fallback only) ----------------
__global__ void k_zero(float* __restrict__ hp) {
  int idx = blockIdx.x * 256 + threadIdx.x;
  ((float4*)hp)[idx] = make_float4(0.f, 0.f, 0.f, 0.f);
}

// ======= k_pre: blocks 0..255 transpose x->hbfT; blocks 256..319 scores =======
// Also zeroes the k_gemm completion counters (block 256).
__global__ __launch_bounds__(256) void k_pre(
    const float* __restrict__ x, const float* __restrict__ a,
    const float* __restrict__ cwp, const float* __restrict__ cbp,
    unsigned short* __restrict__ hbfT, float* __restrict__ Rpg,
    unsigned short* __restrict__ Ebf, int* __restrict__ cnt) {
  const int tid = threadIdx.x;
  const int bid = blockIdx.x;
  const float cw = cwp[0], cb = cbp[0];

  if (bid < 256) {
    __shared__ float t[64][65];
    const int j0 = (bid & 63) * 64, d0 = (bid >> 6) * 64;
    const int r = tid >> 4, c4 = tid & 15;
#pragma unroll
    for (int p = 0; p < 4; p++) {
      const int jj = p * 16 + r;
      const float4 v = *(const float4*)(x + (size_t)(j0 + jj) * DD + d0 + c4 * 4);
      t[jj][c4 * 4 + 0] = v.x * cw + cb;
      t[jj][c4 * 4 + 1] = v.y * cw + cb;
      t[jj][c4 * 4 + 2] = v.z * cw + cb;
      t[jj][c4 * 4 + 3] = v.w * cw + cb;
    }
    __syncthreads();
    const int jc = (tid & 15) * 4, db = tid >> 4;
#pragma unroll
    for (int p = 0; p < 4; p++) {
      const int dd = p * 16 + db;
      const unsigned l0 = f2bf(t[jc + 0][dd]);
      const unsigned l1 = f2bf(t[jc + 1][dd]);
      const unsigned l2 = f2bf(t[jc + 2][dd]);
      const unsigned l3 = f2bf(t[jc + 3][dd]);
      uint2 val;
      val.x = l0 | (l1 << 16);
      val.y = l2 | (l3 << 16);
      *(uint2*)(hbfT + (size_t)(d0 + dd) * NN + j0 + jc) = val;
    }
  } else {
    if (bid == 256 && tid < 64) cnt[tid] = 0;
    const int ln = tid >> 2, qd = (tid & 3) * 64;
    const int node = (bid - 256) * 64 + ln;
    float p1[HH] = {0.f, 0.f, 0.f, 0.f}, p2[HH] = {0.f, 0.f, 0.f, 0.f};
#pragma unroll
    for (int k = 0; k < 16; k++) {
      const int d = qd + k * 4;
      const float4 v = *(const float4*)(x + (size_t)node * DD + d);
      const float h0 = v.x * cw + cb, h1 = v.y * cw + cb;
      const float h2 = v.z * cw + cb, h3 = v.w * cw + cb;
#pragma unroll
      for (int h = 0; h < HH; h++) {
        const float4 a1 = *(const float4*)(a + h * 512 + d);
        const float4 a2 = *(const float4*)(a + h * 512 + 256 + d);
        p1[h] += h0 * a1.x + h1 * a1.y + h2 * a1.z + h3 * a1.w;
        p2[h] += h0 * a2.x + h1 * a2.y + h2 * a2.z + h3 * a2.w;
      }
    }
#pragma unroll
    for (int off = 1; off <= 2; off <<= 1) {
#pragma unroll
      for (int h = 0; h < HH; h++) {
        p1[h] += __shfl_xor(p1[h], off);
        p2[h] += __shfl_xor(p2[h], off);
      }
    }
    if ((tid & 3) == 0) {
#pragma unroll
      for (int h = 0; h < HH; h++) {
        Rpg[h * NN + node] = __expf(p1[h]);
        Ebf[h * NN + node] = f2bf(__expf(p2[h]));
      }
    }
  }
}

// ======= k_zw: 1 row/block (round-8 proven), unshifted softmax, register P =======
__global__ __launch_bounds__(256) void k_zw(
    const int* __restrict__ adj, const float* __restrict__ Rpg,
    const unsigned short* __restrict__ Ebf, unsigned short* __restrict__ Wm) {
  __shared__ float red[4][HH];
  __shared__ float sZi[HH];

  const int i = blockIdx.x;
  const int tid = threadIdx.x;
  const float C = 0.36787944117144233f;   // e^-1
  float Rp[HH], z[HH];
#pragma unroll
  for (int h = 0; h < HH; h++) {
    Rp[h] = Rpg[h * NN + i];
    z[h] = 0.f;
  }
  unsigned P[4][HH][2];
  const int4* arow = (const int4*)(adj + (size_t)i * NN);
#pragma unroll
  for (int k = 0; k < 4; k++) {
    const int j4 = tid + k * 256;
    const int4 av = arow[j4];
    const bool m0 = av.x > 0, m1 = av.y > 0, m2 = av.z > 0, m3 = av.w > 0;
#pragma unroll
    for (int h = 0; h < HH; h++) {
      const uint2 e2 = *(const uint2*)(Ebf + (size_t)h * NN + j4 * 4);
      const float E0 = __uint_as_float(e2.x << 16);
      const float E1 = __uint_as_float(e2.x & 0xffff0000u);
      const float E2 = __uint_as_float(e2.y << 16);
      const float E3 = __uint_as_float(e2.y & 0xffff0000u);
      float u, p0, p1, p2, p3;
      u = Rp[h] * E0; p0 = u > 1.f ? u : C * __expf(u); p0 = m0 ? p0 : 0.f;
      u = Rp[h] * E1; p1 = u > 1.f ? u : C * __expf(u); p1 = m1 ? p1 : 0.f;
      u = Rp[h] * E2; p2 = u > 1.f ? u : C * __expf(u); p2 = m2 ? p2 : 0.f;
      u = Rp[h] * E3; p3 = u > 1.f ? u : C * __expf(u); p3 = m3 ? p3 : 0.f;
      z[h] += (p0 + p1) + (p2 + p3);
      P[k][h][0] = f2bf_pk(p0, p1);
      P[k][h][1] = f2bf_pk(p2, p3);
    }
  }
#pragma unroll
  for (int h = 0; h < HH; h++) {
#pragma unroll
    for (int off = 32; off; off >>= 1) z[h] += __shfl_xor(z[h], off);
  }
  const int lane = tid & 63, wv = tid >> 6;
  if (lane == 0) {
#pragma unroll
    for (int h = 0; h < HH; h++) red[wv][h] = z[h];
  }
  __syncthreads();
  if (tid < HH) {
    const float zt = red[0][tid] + red[1][tid] + red[2][tid] + red[3][tid];
    sZi[tid] = zt > 0.f ? 0.25f / zt : 0.f;
  }
  __syncthreads();
  float Zi[HH];
#pragma unroll
  for (int h = 0; h < HH; h++) Zi[h] = sZi[h];

  unsigned* wrow = (unsigned*)(Wm + (size_t)i * NN);
#pragma unroll
  for (int k = 0; k < 4; k++) {
    const int j4 = tid + k * 256;
    float w0 = 0.f, w1 = 0.f, w2 = 0.f, w3 = 0.f;
#pragma unroll
    for (int h = 0; h < HH; h++) {
      const unsigned pa = P[k][h][0];
      const unsigned pb = P[k][h][1];
      w0 += __uint_as_float(pa << 16) * Zi[h];
      w1 += __uint_as_float(pa & 0xffff0000u) * Zi[h];
      w2 += __uint_as_float(pb << 16) * Zi[h];
      w3 += __uint_as_float(pb & 0xffff0000u) * Zi[h];
    }
    wrow[j4 * 2] = f2bf_pk(w0, w1);
    wrow[j4 * 2 + 1] = f2bf_pk(w2, w3);
  }
}

// ======= k_gemm: MFMA GEMM + fused epilogue (last split-block per row-block) =======
__global__ __launch_bounds__(256) void k_gemm(
    const unsigned short* __restrict__ Wm, const unsigned short* __restrict__ hbfT,
    float* __restrict__ hpOut, int useSplit,
    const float* __restrict__ x, const float* __restrict__ cwp,
    const float* __restrict__ cbp, const float* __restrict__ bias,
    float* __restrict__ out, int* __restrict__ cnt) {
  __shared__ __align__(16) unsigned short sA[64 * 64];    // 8 KB  W tile
  __shared__ __align__(16) unsigned short sB[256 * 64];   // 32 KB h^T tile
  const int tid = threadIdx.x;
  const int wv = tid >> 6, lane = tid & 63;
  const int m16 = lane & 15, q = lane >> 4, m7 = m16 & 7;
  const int rb = blockIdx.x >> 3, sp = blockIdx.x & 7;
  const int i0 = rb * 64;
  const int jlo = sp * (NN / SPLIT);
  const int lr = lane >> 3;
  const int lk8 = (lane & 7) ^ lr;

  float4v acc[4][4];
#pragma unroll
  for (int a = 0; a < 4; a++)
#pragma unroll
    for (int b = 0; b < 4; b++) acc[a][b] = (float4v)0.f;

  for (int kt = 0; kt < (NN / SPLIT) / BKG; kt++) {
    const int j0 = jlo + kt * BKG;
    __syncthreads();
#pragma unroll
    for (int t = 0; t < 2; t++) {
      const int r0 = wv * 16 + t * 8;
      gld16(sA + r0 * 64, Wm + (size_t)(i0 + r0 + lr) * NN + j0 + lk8 * 8);
    }
#pragma unroll
    for (int t = 0; t < 8; t++) {
      const int r0 = wv * 64 + t * 8;
      gld16(sB + r0 * 64, hbfT + (size_t)(r0 + lr) * NN + j0 + lk8 * 8);
    }
    __syncthreads();
#pragma unroll
    for (int ks = 0; ks < 2; ks++) {
      const int kp = ((ks * 4 + q) ^ m7) * 8;
      short8 aF[4], bF[4];
#pragma unroll
      for (int it = 0; it < 4; it++)
        aF[it] = *(const short8*)(sA + (it * 16 + m16) * 64 + kp);
#pragma unroll
      for (int dt = 0; dt < 4; dt++)
        bF[dt] = *(const short8*)(sB + (wv * 64 + dt * 16 + m16) * 64 + kp);
#pragma unroll
      for (int it = 0; it < 4; it++)
#pragma unroll
        for (int dt = 0; dt < 4; dt++)
          acc[it][dt] = __builtin_amdgcn_mfma_f32_16x16x32_bf16(aF[it], bF[dt], acc[it][dt], 0, 0, 0);
    }
  }

  if (useSplit) {
    float* base = hpOut + (size_t)sp * NN * DD;
#pragma unroll
    for (int it = 0; it < 4; it++)
#pragma unroll
      for (int dt = 0; dt < 4; dt++) {
        const int d = wv * 64 + dt * 16 + m16;
#pragma unroll
        for (int rg = 0; rg < 4; rg++)
          base[(size_t)(i0 + it * 16 + q * 4 + rg) * DD + d] = acc[it][dt][rg];
      }
    // ---- completion: last split-block of this row-block runs the epilogue ----
    __threadfence();
    __shared__ int lastFlag;
    if (tid == 0) lastFlag = (atomicAdd(&cnt[rb], 1) == SPLIT - 1) ? 1 : 0;
    __syncthreads();
    if (lastFlag) {
      __threadfence();
      const float cw = cwp[0], cb = cbp[0];
      const int d4 = lane * 4;
      const float4 bv = *(const float4*)(bias + d4);
      for (int r = wv; r < 64; r += 4) {
        const int i = i0 + r;
        float4 pv = make_float4(0.f, 0.f, 0.f, 0.f);
#pragma unroll
        for (int s = 0; s < SPLIT; s++) {
          const float4 t = *(const float4*)(hpOut + (size_t)s * NN * DD + (size_t)i * DD + d4);
          pv.x += t.x; pv.y += t.y; pv.z += t.z; pv.w += t.w;
        }
        const float4 xv = *(const float4*)(x + (size_t)i * DD + d4);
        float4 v;
        v.x = 0.5f * pv.x + 0.5f * (xv.x * cw + cb);
        v.y = 0.5f * pv.y + 0.5f * (xv.y * cw + cb);
        v.z = 0.5f * pv.z + 0.5f * (xv.z * cw + cb);
        v.w = 0.5f * pv.w + 0.5f * (xv.w * cw + cb);
        v.x = v.x > 0.f ? v.x : expm1f(v.x);
        v.y = v.y > 0.f ? v.y : expm1f(v.y);
        v.z = v.z > 0.f ? v.z : expm1f(v.z);
        v.w = v.w > 0.f ? v.w : expm1f(v.w);
        float ss = v.x * v.x + v.y * v.y + v.z * v.z + v.w * v.w;
#pragma unroll
        for (int off = 32; off; off >>= 1) ss += __shfl_xor(ss, off);
        const float inv = 1.f / fmaxf(sqrtf(ss), 1e-12f);
        float4 o;
        o.x = v.x * inv + bv.x;
        o.y = v.y * inv + bv.y;
        o.z = v.z * inv + bv.z;
        o.w = v.w * inv + bv.w;
        *(float4*)(out + (size_t)i * DD + d4) = o;
      }
    }
  } else {
#pragma unroll
    for (int it = 0; it < 4; it++)
#pragma unroll
      for (int dt = 0; dt < 4; dt++) {
        const int d = wv * 64 + dt * 16 + m16;
#pragma unroll
        for (int rg = 0; rg < 4; rg++)
          atomicAdd(&hpOut[(size_t)(i0 + it * 16 + q * 4 + rg) * DD + d], acc[it][dt][rg]);
      }
  }
}

// ---------------- k_epi (fallback path only) ----------------
__global__ __launch_bounds__(256) void k_epi(
    const float* __restrict__ hp, int nsplit, const float* __restrict__ x,
    const float* __restrict__ cwp, const float* __restrict__ cbp,
    const float* __restrict__ bias, float* __restrict__ out) {
  const int lane = threadIdx.x & 63, wv = threadIdx.x >> 6;
  const int i = blockIdx.x * 4 + wv;
  const float cw = cwp[0], cb = cbp[0];
  const int d4 = lane * 4;
  float4 pv = make_float4(0.f, 0.f, 0.f, 0.f);
  for (int s = 0; s < nsplit; s++) {
    const float4 t = *(const float4*)(hp + (size_t)s * NN * DD + (size_t)i * DD + d4);
    pv.x += t.x; pv.y += t.y; pv.z += t.z; pv.w += t.w;
  }
  const float4 xv = *(const float4*)(x + (size_t)i * DD + d4);
  float4 v;
  v.x = 0.5f * pv.x + 0.5f * (xv.x * cw + cb);
  v.y = 0.5f * pv.y + 0.5f * (xv.y * cw + cb);
  v.z = 0.5f * pv.z + 0.5f * (xv.z * cw + cb);
  v.w = 0.5f * pv.w + 0.5f * (xv.w * cw + cb);
  v.x = v.x > 0.f ? v.x : expm1f(v.x);
  v.y = v.y > 0.f ? v.y : expm1f(v.y);
  v.z = v.z > 0.f ? v.z : expm1f(v.z);
  v.w = v.w > 0.f ? v.w : expm1f(v.w);
  float ss = v.x * v.x + v.y * v.y + v.z * v.z + v.w * v.w;
#pragma unroll
  for (int off = 32; off; off >>= 1) ss += __shfl_xor(ss, off);
  const float inv = 1.f / fmaxf(sqrtf(ss), 1e-12f);
  const float4 bv = *(const float4*)(bias + d4);
  float4 o;
  o.x = v.x * inv + bv.x;
  o.y = v.y * inv + bv.y;
  o.z = v.z * inv + bv.z;
  o.w = v.w * inv + bv.w;
  *(float4*)(out + (size_t)i * DD + d4) = o;
}

extern "C" void kernel_launch(void* const* d_in, const int* in_sizes, int n_in,
                              void* d_out, int out_size, void* d_ws, size_t ws_size,
                              hipStream_t stream) {
  const float* x = (const float*)d_in[0];
  const int* adj = (const int*)d_in[1];
  const float* cw = (const float*)d_in[2];
  const float* cb = (const float*)d_in[3];
  const float* a = (const float*)d_in[4];
  const float* bias = (const float*)d_in[5];
  float* out = (float*)d_out;
  float* ws = (float*)d_ws;

  // layout (float units): Rpg | Ebf | hbfT | Wm | hp | cnt
  float* Rpg = ws;                                        // 16384 floats
  unsigned short* Ebf = (unsigned short*)(ws + 16384);    // 16384 shorts
  unsigned short* hbfT = (unsigned short*)(ws + 24576);   // 1M shorts
  unsigned short* Wm = (unsigned short*)(ws + 24576 + 524288);  // 16M shorts
  float* hp = ws + 24576 + 524288 + 8388608;              // SPLIT * N * D
  int* cnt = (int*)(ws + 24576 + 524288 + 8388608 + (size_t)SPLIT * NN * DD);

  const size_t needSplit =
      (size_t)(24576 + 524288 + 8388608 + (size_t)SPLIT * NN * DD + 64) * 4;
  const int useSplit = (ws_size >= needSplit) ? 1 : 0;

  if (!useSplit) hipLaunchKernelGGL(k_zero, dim3(1024), dim3(256), 0, stream, hp);
  hipLaunchKernelGGL(k_pre, dim3(320), dim3(256), 0, stream, x, a, cw, cb, hbfT, Rpg, Ebf, cnt);
  hipLaunchKernelGGL(k_zw, dim3(NN), dim3(256), 0, stream, adj, Rpg, Ebf, Wm);
  hipLaunchKernelGGL(k_gemm, dim3(64 * SPLIT), dim3(256), 0, stream, Wm, hbfT, hp, useSplit,
                     x, cw, cb, bias, out, cnt);
  if (!useSplit)
    hipLaunchKernelGGL(k_epi, dim3(1024), dim3(256), 0, stream, hp, 1, x, cw, cb, bias, out);
}

// Round 12
// 169.446 us; speedup vs baseline: 1.5751x; 1.5751x over previous
//
#include <hip/hip_runtime.h>
#include <math.h>

#define NN 4096
#define DD 256
#define HH 4
#define SPLIT 8
#define BKG 64

typedef short short8 __attribute__((ext_vector_type(8)));
typedef float float4v __attribute__((ext_vector_type(4)));

__device__ __forceinline__ unsigned short f2bf(float f) {
  unsigned u = __float_as_uint(f);
  u += 0x7FFF + ((u >> 16) & 1);   // RNE
  return (unsigned short)(u >> 16);
}
__device__ __forceinline__ unsigned f2bf_pk(float a, float b) {
  unsigned ua = __float_as_uint(a); ua += 0x7FFF + ((ua >> 16) & 1);
  unsigned ub = __float_as_uint(b); ub += 0x7FFF + ((ub >> 16) & 1);
  return __builtin_amdgcn_perm(ub, ua, 0x07060302);
}
__device__ __forceinline__ void gld16(void* lds, const void* gp) {
  __builtin_amdgcn_global_load_lds(
      (const __attribute__((address_space(1))) unsigned int*)gp,
      (__attribute__((address_space(3))) unsigned int*)lds, 16, 0, 0);
}

// ---------------- zero hp (atomic fallback only) ----------------
__global__ void k_zero(float* __restrict__ hp) {
  int idx = blockIdx.x * 256 + threadIdx.x;
  ((float4*)hp)[idx] = make_float4(0.f, 0.f, 0.f, 0.f);
}

// ======= k_pre: blocks 0..255 transpose x->hbfT; blocks 256..319 scores =======
__global__ __launch_bounds__(256) void k_pre(
    const float* __restrict__ x, const float* __restrict__ a,
    const float* __restrict__ cwp, const float* __restrict__ cbp,
    unsigned short* __restrict__ hbfT, float* __restrict__ Rpg,
    unsigned short* __restrict__ Ebf) {
  const int tid = threadIdx.x;
  const int bid = blockIdx.x;
  const float cw = cwp[0], cb = cbp[0];

  if (bid < 256) {
    __shared__ float t[64][65];
    const int j0 = (bid & 63) * 64, d0 = (bid >> 6) * 64;
    const int r = tid >> 4, c4 = tid & 15;
#pragma unroll
    for (int p = 0; p < 4; p++) {
      const int jj = p * 16 + r;
      const float4 v = *(const float4*)(x + (size_t)(j0 + jj) * DD + d0 + c4 * 4);
      t[jj][c4 * 4 + 0] = v.x * cw + cb;
      t[jj][c4 * 4 + 1] = v.y * cw + cb;
      t[jj][c4 * 4 + 2] = v.z * cw + cb;
      t[jj][c4 * 4 + 3] = v.w * cw + cb;
    }
    __syncthreads();
    const int jc = (tid & 15) * 4, db = tid >> 4;
#pragma unroll
    for (int p = 0; p < 4; p++) {
      const int dd = p * 16 + db;
      const unsigned l0 = f2bf(t[jc + 0][dd]);
      const unsigned l1 = f2bf(t[jc + 1][dd]);
      const unsigned l2 = f2bf(t[jc + 2][dd]);
      const unsigned l3 = f2bf(t[jc + 3][dd]);
      uint2 val;
      val.x = l0 | (l1 << 16);
      val.y = l2 | (l3 << 16);
      *(uint2*)(hbfT + (size_t)(d0 + dd) * NN + j0 + jc) = val;
    }
  } else {
    const int ln = tid >> 2, qd = (tid & 3) * 64;
    const int node = (bid - 256) * 64 + ln;
    float p1[HH] = {0.f, 0.f, 0.f, 0.f}, p2[HH] = {0.f, 0.f, 0.f, 0.f};
#pragma unroll
    for (int k = 0; k < 16; k++) {
      const int d = qd + k * 4;
      const float4 v = *(const float4*)(x + (size_t)node * DD + d);
      const float h0 = v.x * cw + cb, h1 = v.y * cw + cb;
      const float h2 = v.z * cw + cb, h3 = v.w * cw + cb;
#pragma unroll
      for (int h = 0; h < HH; h++) {
        const float4 a1 = *(const float4*)(a + h * 512 + d);
        const float4 a2 = *(const float4*)(a + h * 512 + 256 + d);
        p1[h] += h0 * a1.x + h1 * a1.y + h2 * a1.z + h3 * a1.w;
        p2[h] += h0 * a2.x + h1 * a2.y + h2 * a2.z + h3 * a2.w;
      }
    }
#pragma unroll
    for (int off = 1; off <= 2; off <<= 1) {
#pragma unroll
      for (int h = 0; h < HH; h++) {
        p1[h] += __shfl_xor(p1[h], off);
        p2[h] += __shfl_xor(p2[h], off);
      }
    }
    if ((tid & 3) == 0) {
#pragma unroll
      for (int h = 0; h < HH; h++) {
        Rpg[h * NN + node] = __expf(p1[h]);
        Ebf[h * NN + node] = f2bf(__expf(p2[h]));
      }
    }
  }
}

// ======= k_zw: 4 rows SEQUENTIAL per block (grid 1024), round-8 per-row body =======
// p = exp(elu(t)): t>0 (u>1) -> u ; t<=0 -> exp(u-1) = C*exp(u) (ternary required!)
__global__ __launch_bounds__(256) void k_zw(
    const int* __restrict__ adj, const float* __restrict__ Rpg,
    const unsigned short* __restrict__ Ebf, unsigned short* __restrict__ Wm) {
  __shared__ float red[4][HH];
  __shared__ float sZi[HH];

  const int tid = threadIdx.x;
  const int lane = tid & 63, wv = tid >> 6;
  const float C = 0.36787944117144233f;   // e^-1

#pragma unroll 1
  for (int rr = 0; rr < 4; rr++) {
    const int i = blockIdx.x * 4 + rr;
    float Rp[HH], z[HH];
#pragma unroll
    for (int h = 0; h < HH; h++) {
      Rp[h] = Rpg[h * NN + i];
      z[h] = 0.f;
    }
    unsigned P[4][HH][2];
    const int4* arow = (const int4*)(adj + (size_t)i * NN);
#pragma unroll
    for (int k = 0; k < 4; k++) {
      const int j4 = tid + k * 256;
      const int4 av = arow[j4];
      const bool m0 = av.x > 0, m1 = av.y > 0, m2 = av.z > 0, m3 = av.w > 0;
#pragma unroll
      for (int h = 0; h < HH; h++) {
        const uint2 e2 = *(const uint2*)(Ebf + (size_t)h * NN + j4 * 4);
        const float E0 = __uint_as_float(e2.x << 16);
        const float E1 = __uint_as_float(e2.x & 0xffff0000u);
        const float E2 = __uint_as_float(e2.y << 16);
        const float E3 = __uint_as_float(e2.y & 0xffff0000u);
        float u, p0, p1, p2, p3;
        u = Rp[h] * E0; p0 = u > 1.f ? u : C * __expf(u); p0 = m0 ? p0 : 0.f;
        u = Rp[h] * E1; p1 = u > 1.f ? u : C * __expf(u); p1 = m1 ? p1 : 0.f;
        u = Rp[h] * E2; p2 = u > 1.f ? u : C * __expf(u); p2 = m2 ? p2 : 0.f;
        u = Rp[h] * E3; p3 = u > 1.f ? u : C * __expf(u); p3 = m3 ? p3 : 0.f;
        z[h] += (p0 + p1) + (p2 + p3);
        P[k][h][0] = f2bf_pk(p0, p1);
        P[k][h][1] = f2bf_pk(p2, p3);
      }
    }
#pragma unroll
    for (int h = 0; h < HH; h++) {
#pragma unroll
      for (int off = 32; off; off >>= 1) z[h] += __shfl_xor(z[h], off);
    }
    if (lane == 0) {
#pragma unroll
      for (int h = 0; h < HH; h++) red[wv][h] = z[h];
    }
    __syncthreads();
    if (tid < HH) {
      const float zt = red[0][tid] + red[1][tid] + red[2][tid] + red[3][tid];
      sZi[tid] = zt > 0.f ? 0.25f / zt : 0.f;
    }
    __syncthreads();
    float Zi[HH];
#pragma unroll
    for (int h = 0; h < HH; h++) Zi[h] = sZi[h];

    unsigned* wrow = (unsigned*)(Wm + (size_t)i * NN);
#pragma unroll
    for (int k = 0; k < 4; k++) {
      const int j4 = tid + k * 256;
      float w0 = 0.f, w1 = 0.f, w2 = 0.f, w3 = 0.f;
#pragma unroll
      for (int h = 0; h < HH; h++) {
        const unsigned pa = P[k][h][0];
        const unsigned pb = P[k][h][1];
        w0 += __uint_as_float(pa << 16) * Zi[h];
        w1 += __uint_as_float(pa & 0xffff0000u) * Zi[h];
        w2 += __uint_as_float(pb << 16) * Zi[h];
        w3 += __uint_as_float(pb & 0xffff0000u) * Zi[h];
      }
      wrow[j4 * 2] = f2bf_pk(w0, w1);
      wrow[j4 * 2 + 1] = f2bf_pk(w2, w3);
    }
    __syncthreads();   // red/sZi reused next row
  }
}

// ======= k_gemm: MFMA GEMM, global_load_lds staging, XOR-swizzled LDS =======
__global__ __launch_bounds__(256) void k_gemm(
    const unsigned short* __restrict__ Wm, const unsigned short* __restrict__ hbfT,
    float* __restrict__ hpOut, int useSplit) {
  __shared__ __align__(16) unsigned short sA[64 * 64];    // 8 KB  W tile
  __shared__ __align__(16) unsigned short sB[256 * 64];   // 32 KB h^T tile
  const int tid = threadIdx.x;
  const int wv = tid >> 6, lane = tid & 63;
  const int m16 = lane & 15, q = lane >> 4, m7 = m16 & 7;
  const int rb = blockIdx.x >> 3, sp = blockIdx.x & 7;
  const int i0 = rb * 64;
  const int jlo = sp * (NN / SPLIT);
  const int lr = lane >> 3;
  const int lk8 = (lane & 7) ^ lr;

  float4v acc[4][4];
#pragma unroll
  for (int a = 0; a < 4; a++)
#pragma unroll
    for (int b = 0; b < 4; b++) acc[a][b] = (float4v)0.f;

  for (int kt = 0; kt < (NN / SPLIT) / BKG; kt++) {
    const int j0 = jlo + kt * BKG;
    __syncthreads();
#pragma unroll
    for (int t = 0; t < 2; t++) {
      const int r0 = wv * 16 + t * 8;
      gld16(sA + r0 * 64, Wm + (size_t)(i0 + r0 + lr) * NN + j0 + lk8 * 8);
    }
#pragma unroll
    for (int t = 0; t < 8; t++) {
      const int r0 = wv * 64 + t * 8;
      gld16(sB + r0 * 64, hbfT + (size_t)(r0 + lr) * NN + j0 + lk8 * 8);
    }
    __syncthreads();
#pragma unroll
    for (int ks = 0; ks < 2; ks++) {
      const int kp = ((ks * 4 + q) ^ m7) * 8;
      short8 aF[4], bF[4];
#pragma unroll
      for (int it = 0; it < 4; it++)
        aF[it] = *(const short8*)(sA + (it * 16 + m16) * 64 + kp);
#pragma unroll
      for (int dt = 0; dt < 4; dt++)
        bF[dt] = *(const short8*)(sB + (wv * 64 + dt * 16 + m16) * 64 + kp);
#pragma unroll
      for (int it = 0; it < 4; it++)
#pragma unroll
        for (int dt = 0; dt < 4; dt++)
          acc[it][dt] = __builtin_amdgcn_mfma_f32_16x16x32_bf16(aF[it], bF[dt], acc[it][dt], 0, 0, 0);
    }
  }

  if (useSplit) {
    float* base = hpOut + (size_t)sp * NN * DD;
#pragma unroll
    for (int it = 0; it < 4; it++)
#pragma unroll
      for (int dt = 0; dt < 4; dt++) {
        const int d = wv * 64 + dt * 16 + m16;
#pragma unroll
        for (int rg = 0; rg < 4; rg++)
          base[(size_t)(i0 + it * 16 + q * 4 + rg) * DD + d] = acc[it][dt][rg];
      }
  } else {
#pragma unroll
    for (int it = 0; it < 4; it++)
#pragma unroll
      for (int dt = 0; dt < 4; dt++) {
        const int d = wv * 64 + dt * 16 + m16;
#pragma unroll
        for (int rg = 0; rg < 4; rg++)
          atomicAdd(&hpOut[(size_t)(i0 + it * 16 + q * 4 + rg) * DD + d], acc[it][dt][rg]);
      }
  }
}

// ---------------- k_epi ----------------
__global__ __launch_bounds__(256) void k_epi(
    const float* __restrict__ hp, int nsplit, const float* __restrict__ x,
    const float* __restrict__ cwp, const float* __restrict__ cbp,
    const float* __restrict__ bias, float* __restrict__ out) {
  const int lane = threadIdx.x & 63, wv = threadIdx.x >> 6;
  const int i = blockIdx.x * 4 + wv;
  const float cw = cwp[0], cb = cbp[0];
  const int d4 = lane * 4;
  float4 pv = make_float4(0.f, 0.f, 0.f, 0.f);
  for (int s = 0; s < nsplit; s++) {
    const float4 t = *(const float4*)(hp + (size_t)s * NN * DD + (size_t)i * DD + d4);
    pv.x += t.x; pv.y += t.y; pv.z += t.z; pv.w += t.w;
  }
  const float4 xv = *(const float4*)(x + (size_t)i * DD + d4);
  float4 v;
  v.x = 0.5f * pv.x + 0.5f * (xv.x * cw + cb);
  v.y = 0.5f * pv.y + 0.5f * (xv.y * cw + cb);
  v.z = 0.5f * pv.z + 0.5f * (xv.z * cw + cb);
  v.w = 0.5f * pv.w + 0.5f * (xv.w * cw + cb);
  v.x = v.x > 0.f ? v.x : expm1f(v.x);
  v.y = v.y > 0.f ? v.y : expm1f(v.y);
  v.z = v.z > 0.f ? v.z : expm1f(v.z);
  v.w = v.w > 0.f ? v.w : expm1f(v.w);
  float ss = v.x * v.x + v.y * v.y + v.z * v.z + v.w * v.w;
#pragma unroll
  for (int off = 32; off; off >>= 1) ss += __shfl_xor(ss, off);
  const float inv = 1.f / fmaxf(sqrtf(ss), 1e-12f);
  const float4 bv = *(const float4*)(bias + d4);
  float4 o;
  o.x = v.x * inv + bv.x;
  o.y = v.y * inv + bv.y;
  o.z = v.z * inv + bv.z;
  o.w = v.w * inv + bv.w;
  *(float4*)(out + (size_t)i * DD + d4) = o;
}

extern "C" void kernel_launch(void* const* d_in, const int* in_sizes, int n_in,
                              void* d_out, int out_size, void* d_ws, size_t ws_size,
                              hipStream_t stream) {
  const float* x = (const float*)d_in[0];
  const int* adj = (const int*)d_in[1];
  const float* cw = (const float*)d_in[2];
  const float* cb = (const float*)d_in[3];
  const float* a = (const float*)d_in[4];
  const float* bias = (const float*)d_in[5];
  float* out = (float*)d_out;
  float* ws = (float*)d_ws;

  // layout (float units): Rpg | Ebf | hbfT | Wm | hp
  float* Rpg = ws;                                        // 16384 floats
  unsigned short* Ebf = (unsigned short*)(ws + 16384);    // 16384 shorts
  unsigned short* hbfT = (unsigned short*)(ws + 24576);   // 1M shorts
  unsigned short* Wm = (unsigned short*)(ws + 24576 + 524288);  // 16M shorts
  float* hp = ws + 24576 + 524288 + 8388608;              // SPLIT * N * D

  const size_t needSplit =
      (size_t)(24576 + 524288 + 8388608 + (size_t)SPLIT * NN * DD) * 4;
  const int useSplit = (ws_size >= needSplit) ? 1 : 0;
  const int nsplit = useSplit ? SPLIT : 1;

  if (!useSplit) hipLaunchKernelGGL(k_zero, dim3(1024), dim3(256), 0, stream, hp);
  hipLaunchKernelGGL(k_pre, dim3(320), dim3(256), 0, stream, x, a, cw, cb, hbfT, Rpg, Ebf);
  hipLaunchKernelGGL(k_zw, dim3(NN / 4), dim3(256), 0, stream, adj, Rpg, Ebf, Wm);
  hipLaunchKernelGGL(k_gemm, dim3(64 * SPLIT), dim3(256), 0, stream, Wm, hbfT, hp, useSplit);
  hipLaunchKernelGGL(k_epi, dim3(1024), dim3(256), 0, stream, hp, nsplit, x, cw, cb, bias, out);
}

// Round 13
// 167.206 us; speedup vs baseline: 1.5962x; 1.0134x over previous
//
#include <hip/hip_runtime.h>
#include <math.h>

#define NN 4096
#define DD 256
#define HH 4
#define SPLIT 8
#define BKG 64

typedef short short8 __attribute__((ext_vector_type(8)));
typedef float float4v __attribute__((ext_vector_type(4)));

__device__ __forceinline__ unsigned short f2bf(float f) {
  unsigned u = __float_as_uint(f);
  u += 0x7FFF + ((u >> 16) & 1);   // RNE
  return (unsigned short)(u >> 16);
}
__device__ __forceinline__ unsigned f2bf_pk(float a, float b) {
  unsigned ua = __float_as_uint(a); ua += 0x7FFF + ((ua >> 16) & 1);
  unsigned ub = __float_as_uint(b); ub += 0x7FFF + ((ub >> 16) & 1);
  return __builtin_amdgcn_perm(ub, ua, 0x07060302);
}
__device__ __forceinline__ void gld16(void* lds, const void* gp) {
  __builtin_amdgcn_global_load_lds(
      (const __attribute__((address_space(1))) unsigned int*)gp,
      (__attribute__((address_space(3))) unsigned int*)lds, 16, 0, 0);
}

// ---------------- zero hp (atomic fallback only) ----------------
__global__ void k_zero(float* __restrict__ hp) {
  int idx = blockIdx.x * 256 + threadIdx.x;
  ((float4*)hp)[idx] = make_float4(0.f, 0.f, 0.f, 0.f);
}

// ======= k_pre: blocks 0..255 transpose x->hbfT; blocks 256..319 scores =======
// Rp[h][i] = exp(s1), Ebf[h][j] = bf16(exp(s2)); unshifted softmax is safe:
// e <= s1+s2 < ~40, exp(40)=2e17 << fp32 max
__global__ __launch_bounds__(256) void k_pre(
    const float* __restrict__ x, const float* __restrict__ a,
    const float* __restrict__ cwp, const float* __restrict__ cbp,
    unsigned short* __restrict__ hbfT, float* __restrict__ Rpg,
    unsigned short* __restrict__ Ebf) {
  const int tid = threadIdx.x;
  const int bid = blockIdx.x;
  const float cw = cwp[0], cb = cbp[0];

  if (bid < 256) {
    __shared__ float t[64][65];
    const int j0 = (bid & 63) * 64, d0 = (bid >> 6) * 64;
    const int r = tid >> 4, c4 = tid & 15;
#pragma unroll
    for (int p = 0; p < 4; p++) {
      const int jj = p * 16 + r;
      const float4 v = *(const float4*)(x + (size_t)(j0 + jj) * DD + d0 + c4 * 4);
      t[jj][c4 * 4 + 0] = v.x * cw + cb;
      t[jj][c4 * 4 + 1] = v.y * cw + cb;
      t[jj][c4 * 4 + 2] = v.z * cw + cb;
      t[jj][c4 * 4 + 3] = v.w * cw + cb;
    }
    __syncthreads();
    const int jc = (tid & 15) * 4, db = tid >> 4;
#pragma unroll
    for (int p = 0; p < 4; p++) {
      const int dd = p * 16 + db;
      const unsigned l0 = f2bf(t[jc + 0][dd]);
      const unsigned l1 = f2bf(t[jc + 1][dd]);
      const unsigned l2 = f2bf(t[jc + 2][dd]);
      const unsigned l3 = f2bf(t[jc + 3][dd]);
      uint2 val;
      val.x = l0 | (l1 << 16);
      val.y = l2 | (l3 << 16);
      *(uint2*)(hbfT + (size_t)(d0 + dd) * NN + j0 + jc) = val;
    }
  } else {
    const int ln = tid >> 2, qd = (tid & 3) * 64;
    const int node = (bid - 256) * 64 + ln;
    float p1[HH] = {0.f, 0.f, 0.f, 0.f}, p2[HH] = {0.f, 0.f, 0.f, 0.f};
#pragma unroll
    for (int k = 0; k < 16; k++) {
      const int d = qd + k * 4;
      const float4 v = *(const float4*)(x + (size_t)node * DD + d);
      const float h0 = v.x * cw + cb, h1 = v.y * cw + cb;
      const float h2 = v.z * cw + cb, h3 = v.w * cw + cb;
#pragma unroll
      for (int h = 0; h < HH; h++) {
        const float4 a1 = *(const float4*)(a + h * 512 + d);
        const float4 a2 = *(const float4*)(a + h * 512 + 256 + d);
        p1[h] += h0 * a1.x + h1 * a1.y + h2 * a1.z + h3 * a1.w;
        p2[h] += h0 * a2.x + h1 * a2.y + h2 * a2.z + h3 * a2.w;
      }
    }
#pragma unroll
    for (int off = 1; off <= 2; off <<= 1) {
#pragma unroll
      for (int h = 0; h < HH; h++) {
        p1[h] += __shfl_xor(p1[h], off);
        p2[h] += __shfl_xor(p2[h], off);
      }
    }
    if ((tid & 3) == 0) {
#pragma unroll
      for (int h = 0; h < HH; h++) {
        Rpg[h * NN + node] = __expf(p1[h]);
        Ebf[h * NN + node] = f2bf(__expf(p2[h]));
      }
    }
  }
}

// ======= k_zw: 1 row/block (round-8 proven best), unshifted softmax, register P =======
// p = exp(elu(t)): t>0 (u>1) -> u ; t<=0 -> exp(u-1) = C*exp(u) (ternary required:
// exp(u-1) >= u for ALL u, so min/max folds are mathematically wrong)
__global__ __launch_bounds__(256) void k_zw(
    const int* __restrict__ adj, const float* __restrict__ Rpg,
    const unsigned short* __restrict__ Ebf, unsigned short* __restrict__ Wm) {
  __shared__ float red[4][HH];
  __shared__ float sZi[HH];

  const int i = blockIdx.x;
  const int tid = threadIdx.x;
  const float C = 0.36787944117144233f;   // e^-1
  float Rp[HH], z[HH];
#pragma unroll
  for (int h = 0; h < HH; h++) {
    Rp[h] = Rpg[h * NN + i];
    z[h] = 0.f;
  }
  unsigned P[4][HH][2];
  const int4* arow = (const int4*)(adj + (size_t)i * NN);
#pragma unroll
  for (int k = 0; k < 4; k++) {
    const int j4 = tid + k * 256;
    const int4 av = arow[j4];
    const bool m0 = av.x > 0, m1 = av.y > 0, m2 = av.z > 0, m3 = av.w > 0;
#pragma unroll
    for (int h = 0; h < HH; h++) {
      const uint2 e2 = *(const uint2*)(Ebf + (size_t)h * NN + j4 * 4);
      const float E0 = __uint_as_float(e2.x << 16);
      const float E1 = __uint_as_float(e2.x & 0xffff0000u);
      const float E2 = __uint_as_float(e2.y << 16);
      const float E3 = __uint_as_float(e2.y & 0xffff0000u);
      float u, p0, p1, p2, p3;
      u = Rp[h] * E0; p0 = u > 1.f ? u : C * __expf(u); p0 = m0 ? p0 : 0.f;
      u = Rp[h] * E1; p1 = u > 1.f ? u : C * __expf(u); p1 = m1 ? p1 : 0.f;
      u = Rp[h] * E2; p2 = u > 1.f ? u : C * __expf(u); p2 = m2 ? p2 : 0.f;
      u = Rp[h] * E3; p3 = u > 1.f ? u : C * __expf(u); p3 = m3 ? p3 : 0.f;
      z[h] += (p0 + p1) + (p2 + p3);
      P[k][h][0] = f2bf_pk(p0, p1);
      P[k][h][1] = f2bf_pk(p2, p3);
    }
  }
#pragma unroll
  for (int h = 0; h < HH; h++) {
#pragma unroll
    for (int off = 32; off; off >>= 1) z[h] += __shfl_xor(z[h], off);
  }
  const int lane = tid & 63, wv = tid >> 6;
  if (lane == 0) {
#pragma unroll
    for (int h = 0; h < HH; h++) red[wv][h] = z[h];
  }
  __syncthreads();
  if (tid < HH) {
    const float zt = red[0][tid] + red[1][tid] + red[2][tid] + red[3][tid];
    sZi[tid] = zt > 0.f ? 0.25f / zt : 0.f;
  }
  __syncthreads();
  float Zi[HH];
#pragma unroll
  for (int h = 0; h < HH; h++) Zi[h] = sZi[h];

  unsigned* wrow = (unsigned*)(Wm + (size_t)i * NN);
#pragma unroll
  for (int k = 0; k < 4; k++) {
    const int j4 = tid + k * 256;
    float w0 = 0.f, w1 = 0.f, w2 = 0.f, w3 = 0.f;
#pragma unroll
    for (int h = 0; h < HH; h++) {
      const unsigned pa = P[k][h][0];
      const unsigned pb = P[k][h][1];
      w0 += __uint_as_float(pa << 16) * Zi[h];
      w1 += __uint_as_float(pa & 0xffff0000u) * Zi[h];
      w2 += __uint_as_float(pb << 16) * Zi[h];
      w3 += __uint_as_float(pb & 0xffff0000u) * Zi[h];
    }
    wrow[j4 * 2] = f2bf_pk(w0, w1);
    wrow[j4 * 2 + 1] = f2bf_pk(w2, w3);
  }
}

// ======= k_gemm: MFMA GEMM, global_load_lds staging, XOR-swizzled LDS =======
__global__ __launch_bounds__(256) void k_gemm(
    const unsigned short* __restrict__ Wm, const unsigned short* __restrict__ hbfT,
    float* __restrict__ hpOut, int useSplit) {
  __shared__ __align__(16) unsigned short sA[64 * 64];    // 8 KB  W tile
  __shared__ __align__(16) unsigned short sB[256 * 64];   // 32 KB h^T tile
  const int tid = threadIdx.x;
  const int wv = tid >> 6, lane = tid & 63;
  const int m16 = lane & 15, q = lane >> 4, m7 = m16 & 7;
  const int rb = blockIdx.x >> 3, sp = blockIdx.x & 7;
  const int i0 = rb * 64;
  const int jlo = sp * (NN / SPLIT);
  const int lr = lane >> 3;
  const int lk8 = (lane & 7) ^ lr;

  float4v acc[4][4];
#pragma unroll
  for (int a = 0; a < 4; a++)
#pragma unroll
    for (int b = 0; b < 4; b++) acc[a][b] = (float4v)0.f;

  for (int kt = 0; kt < (NN / SPLIT) / BKG; kt++) {
    const int j0 = jlo + kt * BKG;
    __syncthreads();
#pragma unroll
    for (int t = 0; t < 2; t++) {
      const int r0 = wv * 16 + t * 8;
      gld16(sA + r0 * 64, Wm + (size_t)(i0 + r0 + lr) * NN + j0 + lk8 * 8);
    }
#pragma unroll
    for (int t = 0; t < 8; t++) {
      const int r0 = wv * 64 + t * 8;
      gld16(sB + r0 * 64, hbfT + (size_t)(r0 + lr) * NN + j0 + lk8 * 8);
    }
    __syncthreads();
#pragma unroll
    for (int ks = 0; ks < 2; ks++) {
      const int kp = ((ks * 4 + q) ^ m7) * 8;
      short8 aF[4], bF[4];
#pragma unroll
      for (int it = 0; it < 4; it++)
        aF[it] = *(const short8*)(sA + (it * 16 + m16) * 64 + kp);
#pragma unroll
      for (int dt = 0; dt < 4; dt++)
        bF[dt] = *(const short8*)(sB + (wv * 64 + dt * 16 + m16) * 64 + kp);
#pragma unroll
      for (int it = 0; it < 4; it++)
#pragma unroll
        for (int dt = 0; dt < 4; dt++)
          acc[it][dt] = __builtin_amdgcn_mfma_f32_16x16x32_bf16(aF[it], bF[dt], acc[it][dt], 0, 0, 0);
    }
  }

  if (useSplit) {
    float* base = hpOut + (size_t)sp * NN * DD;
#pragma unroll
    for (int it = 0; it < 4; it++)
#pragma unroll
      for (int dt = 0; dt < 4; dt++) {
        const int d = wv * 64 + dt * 16 + m16;
#pragma unroll
        for (int rg = 0; rg < 4; rg++)
          base[(size_t)(i0 + it * 16 + q * 4 + rg) * DD + d] = acc[it][dt][rg];
      }
  } else {
#pragma unroll
    for (int it = 0; it < 4; it++)
#pragma unroll
      for (int dt = 0; dt < 4; dt++) {
        const int d = wv * 64 + dt * 16 + m16;
#pragma unroll
        for (int rg = 0; rg < 4; rg++)
          atomicAdd(&hpOut[(size_t)(i0 + it * 16 + q * 4 + rg) * DD + d], acc[it][dt][rg]);
      }
  }
}

// ---------------- k_epi ----------------
__global__ __launch_bounds__(256) void k_epi(
    const float* __restrict__ hp, int nsplit, const float* __restrict__ x,
    const float* __restrict__ cwp, const float* __restrict__ cbp,
    const float* __restrict__ bias, float* __restrict__ out) {
  const int lane = threadIdx.x & 63, wv = threadIdx.x >> 6;
  const int i = blockIdx.x * 4 + wv;
  const float cw = cwp[0], cb = cbp[0];
  const int d4 = lane * 4;
  float4 pv = make_float4(0.f, 0.f, 0.f, 0.f);
  for (int s = 0; s < nsplit; s++) {
    const float4 t = *(const float4*)(hp + (size_t)s * NN * DD + (size_t)i * DD + d4);
    pv.x += t.x; pv.y += t.y; pv.z += t.z; pv.w += t.w;
  }
  const float4 xv = *(const float4*)(x + (size_t)i * DD + d4);
  float4 v;
  v.x = 0.5f * pv.x + 0.5f * (xv.x * cw + cb);
  v.y = 0.5f * pv.y + 0.5f * (xv.y * cw + cb);
  v.z = 0.5f * pv.z + 0.5f * (xv.z * cw + cb);
  v.w = 0.5f * pv.w + 0.5f * (xv.w * cw + cb);
  v.x = v.x > 0.f ? v.x : expm1f(v.x);
  v.y = v.y > 0.f ? v.y : expm1f(v.y);
  v.z = v.z > 0.f ? v.z : expm1f(v.z);
  v.w = v.w > 0.f ? v.w : expm1f(v.w);
  float ss = v.x * v.x + v.y * v.y + v.z * v.z + v.w * v.w;
#pragma unroll
  for (int off = 32; off; off >>= 1) ss += __shfl_xor(ss, off);
  const float inv = 1.f / fmaxf(sqrtf(ss), 1e-12f);
  const float4 bv = *(const float4*)(bias + d4);
  float4 o;
  o.x = v.x * inv + bv.x;
  o.y = v.y * inv + bv.y;
  o.z = v.z * inv + bv.z;
  o.w = v.w * inv + bv.w;
  *(float4*)(out + (size_t)i * DD + d4) = o;
}

extern "C" void kernel_launch(void* const* d_in, const int* in_sizes, int n_in,
                              void* d_out, int out_size, void* d_ws, size_t ws_size,
                              hipStream_t stream) {
  const float* x = (const float*)d_in[0];
  const int* adj = (const int*)d_in[1];
  const float* cw = (const float*)d_in[2];
  const float* cb = (const float*)d_in[3];
  const float* a = (const float*)d_in[4];
  const float* bias = (const float*)d_in[5];
  float* out = (float*)d_out;
  float* ws = (float*)d_ws;

  // layout (float units): Rpg | Ebf | hbfT | Wm | hp
  float* Rpg = ws;                                        // 16384 floats
  unsigned short* Ebf = (unsigned short*)(ws + 16384);    // 16384 shorts
  unsigned short* hbfT = (unsigned short*)(ws + 24576);   // 1M shorts
  unsigned short* Wm = (unsigned short*)(ws + 24576 + 524288);  // 16M shorts
  float* hp = ws + 24576 + 524288 + 8388608;              // SPLIT * N * D

  const size_t needSplit =
      (size_t)(24576 + 524288 + 8388608 + (size_t)SPLIT * NN * DD) * 4;
  const int useSplit = (ws_size >= needSplit) ? 1 : 0;
  const int nsplit = useSplit ? SPLIT : 1;

  if (!useSplit) hipLaunchKernelGGL(k_zero, dim3(1024), dim3(256), 0, stream, hp);
  hipLaunchKernelGGL(k_pre, dim3(320), dim3(256), 0, stream, x, a, cw, cb, hbfT, Rpg, Ebf);
  hipLaunchKernelGGL(k_zw, dim3(NN), dim3(256), 0, stream, adj, Rpg, Ebf, Wm);
  hipLaunchKernelGGL(k_gemm, dim3(64 * SPLIT), dim3(256), 0, stream, Wm, hbfT, hp, useSplit);
  hipLaunchKernelGGL(k_epi, dim3(1024), dim3(256), 0, stream, hp, nsplit, x, cw, cb, bias, out);
}